// Round 3
// baseline (683.482 us; speedup 1.0000x reference)
//
#include <hip/hip_runtime.h>
#include <hip/hip_bf16.h>

typedef __hip_bfloat16 bf16;

#define HW 16384

__device__ __forceinline__ float b2f(bf16 v) { return __bfloat162float(v); }
__device__ __forceinline__ bf16 f2b(float v) { return __float2bfloat16(v); }

// ---- ws byte offsets (total footprint: 41 MB, all fp32 inputs read in place) ----
#define OFFB_XP   0u                          // fp32, 131072 floats  (524,288 B)
#define OFFB_K2   524288u                     // fp32, 65,536 floats  (262,144 B)
#define OFFB_V2   786432u                     // fp32, 65,536 floats  (262,144 B) -> 1 MB
#define OFFB_QKV  (1u << 20)                  // bf16, 12,582,912 elems (24 MB) -> 25 MB
                                              //   (qg / res_l overlay this region after k_dw)
#define OFFB_P    (25u << 20)                 // bf16, 4,194,304 elems (8 MB), res_h in-place
#define OFFB_V    (33u << 20)                 // bf16, 4,194,304 elems (8 MB) -> 41 MB

// ---------------- 8x8 avgpool: x (b,128,128,128) fp32 -> xp (b,128,16,16) fp32 ------------
__global__ __launch_bounds__(256) void k_pool(const float* __restrict__ x, float* __restrict__ xp)
{
    int idx = blockIdx.x * 256 + threadIdx.x;   // 131072 total
    int j = idx & 15, i = (idx >> 4) & 15, bc = idx >> 8;   // bc = b*128+c
    const float* src = x + (size_t)bc * HW + (i * 8) * 128 + j * 8;
    float s = 0.f;
    #pragma unroll
    for (int u = 0; u < 8; u++) {
        #pragma unroll
        for (int t = 0; t < 8; t++) s += src[u * 128 + t];
    }
    xp[bc * 256 + i * 16 + j] = s * (1.f / 64.f);
}

// ---------------- kv conv: xp -> k2/v2 fp32 in (b,h,m,d) layout ----------------
__global__ __launch_bounds__(256) void k_kv(const float* __restrict__ xp,
                                            const float* __restrict__ Wkv, const float* __restrict__ bkv,
                                            float* __restrict__ k2, float* __restrict__ v2)
{
    int og = blockIdx.x & 15, b = blockIdx.x >> 4;
    int m = threadIdx.x;
    float xr[128];
    #pragma unroll
    for (int c = 0; c < 128; c++) xr[c] = xp[(b * 128 + c) * 256 + m];
    #pragma unroll 1
    for (int t = 0; t < 8; t++) {
        int o = og * 8 + t;   // 0..127, block-uniform
        const float* w = Wkv + o * 128;
        float s0 = 0.f, s1 = 0.f, s2 = 0.f, s3 = 0.f;
        #pragma unroll
        for (int c = 0; c < 128; c += 4) {
            s0 += w[c] * xr[c]; s1 += w[c + 1] * xr[c + 1];
            s2 += w[c + 2] * xr[c + 2]; s3 += w[c + 3] * xr[c + 3];
        }
        float a = bkv[o] + ((s0 + s1) + (s2 + s3));
        int sb = o >> 6, r = o & 63, gh = r >> 4, dh = r & 15;
        float* dst = sb == 0 ? k2 : v2;
        dst[((b * 4 + gh) * 256 + m) * 16 + dh] = a;
    }
}

// ---------------- qkv conv1x1: x fp32 -> qkv bf16 (b,192,HW). grid (256, 3) ----------------
__global__ __launch_bounds__(256) void k_qkv(const float* __restrict__ x,
                                             const float* __restrict__ Wqkv, const float* __restrict__ bqkv,
                                             bf16* __restrict__ qkv)
{
    int pix = blockIdx.x * 256 + threadIdx.x;
    int b = pix >> 14, n = pix & (HW - 1);
    int g = blockIdx.y;
    const float* xc = x + (size_t)b * 128 * HW + n;
    float xr[128];
    #pragma unroll
    for (int c = 0; c < 128; c++) xr[c] = xc[(size_t)c * HW];
    const float* W = Wqkv + g * 64 * 128;
    const float* bias = bqkv + g * 64;
    bf16* outp = qkv + (size_t)(b * 192 + g * 64) * HW + n;
    #pragma unroll 1
    for (int o = 0; o < 64; o += 4) {
        float a0 = bias[o], a1 = bias[o + 1], a2 = bias[o + 2], a3 = bias[o + 3];
        const float* w0 = W + (o + 0) * 128;
        const float* w1 = W + (o + 1) * 128;
        const float* w2 = W + (o + 2) * 128;
        const float* w3 = W + (o + 3) * 128;
        #pragma unroll
        for (int c = 0; c < 128; c++) {
            float xv = xr[c];
            a0 += w0[c] * xv; a1 += w1[c] * xv; a2 += w2[c] * xv; a3 += w3[c] * xv;
        }
        outp[(o + 0) * HW] = f2b(a0); outp[(o + 1) * HW] = f2b(a1);
        outp[(o + 2) * HW] = f2b(a2); outp[(o + 3) * HW] = f2b(a3);
    }
}

// ---------------- depthwise 3x3 + q*k: qkv -> p (=qd*kd), v (both bf16) ----------------
__global__ __launch_bounds__(256) void k_dw(const bf16* __restrict__ qkv,
                                            const float* __restrict__ Wdw, const float* __restrict__ bdw,
                                            bf16* __restrict__ p, bf16* __restrict__ v)
{
    int nblk = blockIdx.x & 63;
    int bc = blockIdx.x >> 6;       // 0..255
    int c = bc & 63, b = bc >> 6;
    int n = nblk * 256 + threadIdx.x;
    int i = n >> 7, j = n & 127;
    const bf16* in0 = qkv + (size_t)(b * 192 + c) * HW;
    const bf16* in1 = qkv + (size_t)(b * 192 + 64 + c) * HW;
    const bf16* in2 = qkv + (size_t)(b * 192 + 128 + c) * HW;
    float aq = bdw[c], ak = bdw[64 + c], av = bdw[128 + c];
    #pragma unroll
    for (int dy = 0; dy < 3; dy++) {
        int ii = i + dy - 1;
        bool iv = (unsigned)ii < 128u;
        #pragma unroll
        for (int dx = 0; dx < 3; dx++) {
            int jj = j + dx - 1;
            bool ok = iv && ((unsigned)jj < 128u);
            int off = ii * 128 + jj;
            float q0 = ok ? b2f(in0[off]) : 0.f;
            float k0 = ok ? b2f(in1[off]) : 0.f;
            float v0 = ok ? b2f(in2[off]) : 0.f;
            int t = dy * 3 + dx;
            aq += Wdw[c * 9 + t] * q0;
            ak += Wdw[(64 + c) * 9 + t] * k0;
            av += Wdw[(128 + c) * 9 + t] * v0;
        }
    }
    p[(size_t)(b * 64 + c) * HW + n] = f2b(aq * ak);
    v[(size_t)(b * 64 + c) * HW + n] = f2b(av);
}

// ---------------- qg conv1x1: x fp32 -> qg bf16 (b,64,HW) (overlays freed qkv region) -----
__global__ __launch_bounds__(256) void k_qg(const float* __restrict__ x,
                                            const float* __restrict__ Wq, const float* __restrict__ bq,
                                            bf16* __restrict__ qg)
{
    int pix = blockIdx.x * 256 + threadIdx.x;
    int b = pix >> 14, n = pix & (HW - 1);
    const float* xc = x + (size_t)b * 128 * HW + n;
    float xr[128];
    #pragma unroll
    for (int c = 0; c < 128; c++) xr[c] = xc[(size_t)c * HW];
    bf16* outp = qg + (size_t)(b * 64) * HW + n;
    #pragma unroll 1
    for (int o = 0; o < 64; o += 4) {
        float a0 = bq[o], a1 = bq[o + 1], a2 = bq[o + 2], a3 = bq[o + 3];
        const float* w0 = Wq + (o + 0) * 128;
        const float* w1 = Wq + (o + 1) * 128;
        const float* w2 = Wq + (o + 2) * 128;
        const float* w3 = Wq + (o + 3) * 128;
        #pragma unroll
        for (int c = 0; c < 128; c++) {
            float xv = xr[c];
            a0 += w0[c] * xv; a1 += w1[c] * xv; a2 += w2[c] * xv; a3 += w3[c] * xv;
        }
        outp[(o + 0) * HW] = f2b(a0); outp[(o + 1) * HW] = f2b(a1);
        outp[(o + 2) * HW] = f2b(a2); outp[(o + 3) * HW] = f2b(a3);
    }
}

// ---------------- high-freq gate path: p,v -> res_h bf16 (in-place over p) ----------------
// Safe in-place: each thread owns one pixel; reads all 64 channels to regs before writing.
__global__ __launch_bounds__(256) void k_resh(bf16* __restrict__ p, const bf16* __restrict__ v,
                                              const float* __restrict__ Wa1, const float* __restrict__ ba1,
                                              const float* __restrict__ Wa2, const float* __restrict__ ba2)
{
    int pix = blockIdx.x * 256 + threadIdx.x;
    int b = pix >> 14, n = pix & (HW - 1);
    float pr[64];
    #pragma unroll
    for (int c = 0; c < 64; c++) pr[c] = b2f(p[(size_t)(b * 64 + c) * HW + n]);
    float acc[64];
    #pragma unroll
    for (int o = 0; o < 64; o++) acc[o] = ba2[o];
    #pragma unroll 1
    for (int c = 0; c < 64; c++) {
        const float* w = Wa1 + c * 64;
        float s0 = 0.f, s1 = 0.f, s2 = 0.f, s3 = 0.f;
        #pragma unroll
        for (int t = 0; t < 64; t += 4) {
            s0 += w[t] * pr[t]; s1 += w[t + 1] * pr[t + 1];
            s2 += w[t + 2] * pr[t + 2]; s3 += w[t + 3] * pr[t + 3];
        }
        float a = ba1[c] + ((s0 + s1) + (s2 + s3));
        float s = a / (1.f + __expf(-a));   // swish (NaN-safe for finite a)
        // acc[o] += Wa2[o][c] * s   (uniform strided loads, L1-cached 16 KB array)
        #pragma unroll
        for (int o = 0; o < 64; o++) acc[o] += Wa2[o * 64 + c] * s;
    }
    #pragma unroll 1
    for (int o = 0; o < 64; o++) {
        float vv = b2f(v[(size_t)(b * 64 + o) * HW + n]);
        p[(size_t)(b * 64 + o) * HW + n] = f2b(tanhf(acc[o] * 0.25f) * vv);
    }
}

// ---------------- low-freq attention: qg,k2,v2 -> res_l bf16 (in-place over qg) ----------
__global__ __launch_bounds__(256) void k_attn(bf16* __restrict__ qg, const float* __restrict__ k2,
                                              const float* __restrict__ v2)
{
    int h = blockIdx.y, b = blockIdx.z;
    int n = blockIdx.x * 256 + threadIdx.x;
    const float* __restrict__ kb = k2 + (b * 4 + h) * 4096;
    const float* __restrict__ vb = v2 + (b * 4 + h) * 4096;
    float q[16];
    #pragma unroll
    for (int d = 0; d < 16; d++) q[d] = b2f(qg[(size_t)(b * 64 + h * 16 + d) * HW + n]) * 0.25f;
    float o[16];
    #pragma unroll
    for (int d = 0; d < 16; d++) o[d] = 0.f;
    float den = 0.f;
    #pragma unroll 2
    for (int m = 0; m < 256; m++) {
        float s0 = 0.f, s1 = 0.f, s2 = 0.f, s3 = 0.f;
        #pragma unroll
        for (int d = 0; d < 16; d += 4) {
            s0 += q[d] * kb[m * 16 + d]; s1 += q[d + 1] * kb[m * 16 + d + 1];
            s2 += q[d + 2] * kb[m * 16 + d + 2]; s3 += q[d + 3] * kb[m * 16 + d + 3];
        }
        float s = (s0 + s1) + (s2 + s3);
        s = fminf(fmaxf(s, -60.f), 60.f);   // never binds at sane magnitudes
        float e = __expf(s);
        den += e;
        #pragma unroll
        for (int d = 0; d < 16; d++) o[d] += e * vb[m * 16 + d];
    }
    float r = 1.f / den;
    #pragma unroll
    for (int d = 0; d < 16; d++)
        qg[(size_t)(b * 64 + h * 16 + d) * HW + n] = f2b(o[d] * r);
}

// ---------------- final proj conv1x1: [res_h | res_l] -> out fp32. grid (256, 2) ----------
__global__ __launch_bounds__(256) void k_proj(const bf16* __restrict__ resh, const bf16* __restrict__ resl,
                                              const float* __restrict__ Wproj, const float* __restrict__ bproj,
                                              float* __restrict__ out)
{
    int pix = blockIdx.x * 256 + threadIdx.x;
    int b = pix >> 14, n = pix & (HW - 1);
    int g = blockIdx.y;
    float xr[128];
    #pragma unroll
    for (int c = 0; c < 64; c++) xr[c] = b2f(resh[(size_t)(b * 64 + c) * HW + n]);
    #pragma unroll
    for (int c = 0; c < 64; c++) xr[64 + c] = b2f(resl[(size_t)(b * 64 + c) * HW + n]);
    const float* W = Wproj + g * 64 * 128;
    const float* bias = bproj + g * 64;
    float* outp = out + (size_t)(b * 128 + g * 64) * HW + n;
    #pragma unroll 1
    for (int o = 0; o < 64; o += 4) {
        float a0 = bias[o], a1 = bias[o + 1], a2 = bias[o + 2], a3 = bias[o + 3];
        const float* w0 = W + (o + 0) * 128;
        const float* w1 = W + (o + 1) * 128;
        const float* w2 = W + (o + 2) * 128;
        const float* w3 = W + (o + 3) * 128;
        #pragma unroll
        for (int c = 0; c < 128; c++) {
            float xv = xr[c];
            a0 += w0[c] * xv; a1 += w1[c] * xv; a2 += w2[c] * xv; a3 += w3[c] * xv;
        }
        outp[(size_t)(o + 0) * HW] = a0; outp[(size_t)(o + 1) * HW] = a1;
        outp[(size_t)(o + 2) * HW] = a2; outp[(size_t)(o + 3) * HW] = a3;
    }
}

extern "C" void kernel_launch(void* const* d_in, const int* in_sizes, int n_in,
                              void* d_out, int out_size, void* d_ws, size_t ws_size,
                              hipStream_t stream)
{
    (void)in_sizes; (void)n_in; (void)out_size; (void)ws_size;
    const float* x     = (const float*)d_in[0];
    const float* Wqkv  = (const float*)d_in[1];
    const float* bqkv  = (const float*)d_in[2];
    const float* Wdw   = (const float*)d_in[3];
    const float* bdw   = (const float*)d_in[4];
    const float* Wa1   = (const float*)d_in[5];
    const float* ba1   = (const float*)d_in[6];
    const float* Wa2   = (const float*)d_in[7];
    const float* ba2   = (const float*)d_in[8];
    const float* Wq    = (const float*)d_in[9];
    const float* bq    = (const float*)d_in[10];
    const float* Wkv   = (const float*)d_in[11];
    const float* bkv   = (const float*)d_in[12];
    const float* Wproj = (const float*)d_in[13];
    const float* bproj = (const float*)d_in[14];

    char* wsb = (char*)d_ws;
    float* xp  = (float*)(wsb + OFFB_XP);
    float* k2  = (float*)(wsb + OFFB_K2);
    float* v2  = (float*)(wsb + OFFB_V2);
    bf16*  qkv = (bf16*)(wsb + OFFB_QKV);      // later overlaid by qg / res_l
    bf16*  p   = (bf16*)(wsb + OFFB_P);        // later holds res_h in-place
    bf16*  v   = (bf16*)(wsb + OFFB_V);
    bf16*  qg  = qkv;                          // 8 MB inside the 24 MB qkv region
    float* out = (float*)d_out;

    k_pool<<<dim3(512), 256, 0, stream>>>(x, xp);
    k_kv<<<dim3(64), 256, 0, stream>>>(xp, Wkv, bkv, k2, v2);
    k_qkv<<<dim3(256, 3), 256, 0, stream>>>(x, Wqkv, bqkv, qkv);
    k_dw<<<dim3(16384), 256, 0, stream>>>(qkv, Wdw, bdw, p, v);
    k_qg<<<dim3(256), 256, 0, stream>>>(x, Wq, bq, qg);          // qkv region free now
    k_resh<<<dim3(256), 256, 0, stream>>>(p, v, Wa1, ba1, Wa2, ba2);  // res_h in-place
    k_attn<<<dim3(64, 4, 4), 256, 0, stream>>>(qg, k2, v2);      // res_l in-place
    k_proj<<<dim3(256, 2), 256, 0, stream>>>(p, qg, Wproj, bproj, out);
}